// Round 6
// baseline (555.032 us; speedup 1.0000x reference)
//
#include <hip/hip_runtime.h>
#include <hip/hip_bf16.h>
#include <math.h>

// ---------------- problem constants ----------------
static constexpr int NBATCH = 4;
static constexpr int NPTS   = 4096;
static constexpr int BN     = NBATCH * NPTS;   // 16384
static constexpr int KNN    = 20;
static constexpr float BN_EPS = 1e-5f;
static constexpr float SLOPE  = 0.2f;
static constexpr int C0 = 64, C1 = 256, DF = 512, DOUT = 256;

#define FINF __builtin_huge_valf()

typedef short bf16x8 __attribute__((ext_vector_type(8)));
typedef float f32x4  __attribute__((ext_vector_type(4)));

// ---------------- workspace layout (bytes) ----------------
static constexpr size_t OFF_H0     = 0;                    // 4 MB
static constexpr size_t OFF_IDX0   = 4194304;              // 1.25 MB
static constexpr size_t OFF_IDX1   = 5505024;              // 1.25 MB
static constexpr size_t OFF_D2     = 6815744;              // 64 KB
static constexpr size_t OFF_GATE   = 6881280;              // 64 KB
static constexpr size_t OFF_ALPHA  = 6946816;              // 64 KB
static constexpr size_t OFF_SS0    = 7012352;
static constexpr size_t OFF_SS1    = 7012864;
static constexpr size_t OFF_STATS0 = 7014912;
static constexpr size_t OFF_STATS1 = 7015424;
static constexpr size_t OFF_POOLED = 7017472;              // -> end 7,025,664
static constexpr size_t ZERO_OFF   = OFF_STATS0;
static constexpr size_t ZERO_BYTES = 7025664 - 7014912;
static constexpr size_t OFF_P1     = 7025664;              // 16 MB (written by pq1, AFTER knn)
static constexpr size_t OFF_PDU    = OFF_P1;               // S=8: 16384*8*20*4 = 10.49 MB (dead before pq1)
static constexpr size_t OFF_Q1     = 27997184;             // 16 MB
static constexpr size_t OFF_U0     = OFF_Q1;               // 1 MB (layer-0 query rows; dead before pq0 writes P0)
static constexpr size_t OFF_V0     = OFF_Q1 + 1048576;     // 1 MB (layer-0 cand rows)
static constexpr size_t OFF_H1     = 44774400;             // 16 MB -> end 61,551,616
static constexpr size_t OFF_P0     = OFF_Q1;               // 4 MB (dead before Q1 written)
static constexpr size_t OFF_Q0     = OFF_Q1 + 4194304;     // 4 MB
static constexpr size_t OFF_AB     = 61551616;             // 4 MB -> end 65,745,920

// ---------------- helpers ----------------
__device__ inline unsigned short f2bf_rne(float x) {
  unsigned int u = __float_as_uint(x);
  unsigned int lsb = (u >> 16) & 1u;
  u += 0x7fffu + lsb;
  return (unsigned short)(u >> 16);
}
__device__ inline float bf2f(unsigned short s) {
  return __uint_as_float((unsigned int)s << 16);
}
__device__ inline unsigned umn(unsigned a, unsigned b) { return a < b ? a : b; }
// clamp(v, lo, hi) with lo<=hi == sorted-insert slot update, single instr.
// NOTE: when v >= hi the result is hi (identity) -> insert may run UNCONDITIONALLY.
__device__ inline unsigned umed3(unsigned v, unsigned lo, unsigned hi) {
  unsigned d;
  asm("v_med3_u32 %0, %1, %2, %3" : "=v"(d) : "v"(v), "v"(lo), "v"(hi));
  return d;
}

// ---------------- d2 = sum(h*h) ----------------
template<int D>
__global__ __launch_bounds__(256) void d2_kernel(const float* __restrict__ h,
                                                 float* __restrict__ d2) {
  int n = blockIdx.x * 256 + threadIdx.x;
  const float* r = h + (size_t)n * D;
  if constexpr (D % 4 == 0) {
    float s0 = 0.f, s1 = 0.f, s2 = 0.f, s3 = 0.f;
#pragma unroll
    for (int d4 = 0; d4 < D / 4; ++d4) {
      float4 v = ((const float4*)r)[d4];
      s0 += v.x * v.x; s1 += v.y * v.y; s2 += v.z * v.z; s3 += v.w * v.w;
    }
    d2[n] = (s0 + s1) + (s2 + s3);
  } else {
    float s = 0.f;
#pragma unroll
    for (int d = 0; d < D; ++d) s += r[d] * r[d];
    d2[n] = s;
  }
}

// ---------------- bf16 split: H0 [BN][64] f32 -> AB [BN][128] bf16 (A|B) ----------------
__global__ __launch_bounds__(256) void split_kernel(const float* __restrict__ h,
                                                    unsigned short* __restrict__ ab) {
  int t = blockIdx.x * 256 + threadIdx.x;        // over BN*16
  int n = t >> 4, d4 = (t & 15) << 2;
  float4 v = *(const float4*)(h + ((size_t)n << 6) + d4);
  float vv[4] = {v.x, v.y, v.z, v.w};
  unsigned short A[4], B[4];
#pragma unroll
  for (int j = 0; j < 4; ++j) {
    unsigned short a = f2bf_rne(vv[j]);
    A[j] = a;
    B[j] = f2bf_rne(vv[j] - bf2f(a));
  }
  unsigned short* dst = ab + ((size_t)n << 7) + d4;
  *(ushort4*)dst         = make_ushort4(A[0], A[1], A[2], A[3]);
  *(ushort4*)(dst + 64)  = make_ushort4(B[0], B[1], B[2], B[3]);
}

// ---------------- layer-0 packing: U=[A,B,A,B,0..] (queries), V=[A,A,B,B,0..] (cands) ------
// dot(U_q, V_c) = Aq.Ac + Bq.Ac + Aq.Bc + Bq.Bc = exact (Aq+Bq).(Ac+Bc)
__global__ __launch_bounds__(256) void usplit0_kernel(
    const float* __restrict__ x, unsigned short* __restrict__ U0,
    unsigned short* __restrict__ V0) {
  int n = blockIdx.x * 256 + threadIdx.x;
  float v0 = x[(size_t)n * 3], v1 = x[(size_t)n * 3 + 1], v2 = x[(size_t)n * 3 + 2];
  unsigned short A0 = f2bf_rne(v0), A1 = f2bf_rne(v1), A2 = f2bf_rne(v2);
  unsigned short B0 = f2bf_rne(v0 - bf2f(A0));
  unsigned short B1 = f2bf_rne(v1 - bf2f(A1));
  unsigned short B2 = f2bf_rne(v2 - bf2f(A2));
  ushort4 z = make_ushort4(0, 0, 0, 0);
  unsigned short* up = U0 + ((size_t)n << 5);
  ((ushort4*)up)[0] = make_ushort4(A0, A1, A2, B0);
  ((ushort4*)up)[1] = make_ushort4(B1, B2, A0, A1);
  ((ushort4*)up)[2] = make_ushort4(A2, B0, B1, B2);
  ((ushort4*)up)[3] = z; ((ushort4*)up)[4] = z; ((ushort4*)up)[5] = z;
  ((ushort4*)up)[6] = z; ((ushort4*)up)[7] = z;
  unsigned short* vp = V0 + ((size_t)n << 5);
  ((ushort4*)vp)[0] = make_ushort4(A0, A1, A2, A0);
  ((ushort4*)vp)[1] = make_ushort4(A1, A2, B0, B1);
  ((ushort4*)vp)[2] = make_ushort4(B2, B0, B1, B2);
  ((ushort4*)vp)[3] = z; ((ushort4*)vp)[4] = z; ((ushort4*)vp)[5] = z;
  ((ushort4*)vp)[6] = z; ((ushort4*)vp)[7] = z;
}

// ---------------- unified MFMA KNN with in-register selection ----------------
// block = 4 waves, 64 queries (16/wave); candidate split S (grid BN/64*S);
// operand-swapped MFMA: D[cand][query] -> lane (l15,lg) holds 8 cands of query l15
// per chunk in acc regs. key = (dist_bits & 0xFFFFF000) | idx12.
// Insert is UNCONDITIONAL (med3 identity when key >= bd[19]); per-lane lists
// merged via __shfl into lg==0 lanes (union superset -> exact top-20 by key).
template<int KW, int CST, int S>
__global__ __launch_bounds__(256) void knn_mfsel_kernel(
    const unsigned short* __restrict__ cab,   // candidate rows [BN][KW]
    const unsigned short* __restrict__ qab,   // query rows [BN][KW]
    const float* __restrict__ d2,
    unsigned* __restrict__ pdu) {
  constexpr int CS = NPTS / S, NCH = CS / 32;
  __shared__ __align__(16) unsigned short cbuf[2][32 * CST];
  __shared__ __align__(16) float cd2b[2][32];

  int bid = blockIdx.x;
  int s   = bid & (S - 1);
  int qb  = bid / S;
  int b   = qb >> 6;
  int qloc = (qb & 63) * 64;
  int wv = threadIdx.x >> 6, lane = threadIdx.x & 63;
  int l15 = lane & 15, lg = lane >> 4;
  int qg = b * NPTS + qloc + wv * 16 + l15;   // this lane's query row

  bf16x8 af[KW / 32];
#pragma unroll
  for (int kk = 0; kk < KW / 32; ++kk)
    af[kk] = *(const bf16x8*)(qab + (size_t)qg * KW + kk * 32 + lg * 8);
  float d2q = d2[qg];

  unsigned bd[KNN];
#pragma unroll
  for (int k = 0; k < KNN; ++k) bd[k] = 0xFFFFFFFFu;

  int scand = threadIdx.x >> 3, sseg = threadIdx.x & 7;
  const unsigned short* sbase = cab + ((size_t)(b * NPTS + s * CS)) * KW;
  const float* d2base = d2 + b * NPTS + s * CS;

  bf16x8 r0, r1;
  ushort4 r2;
  float rd2 = 0.f;

  // prologue: chunk 0
  if constexpr (KW == 128) {
    const unsigned short* src = sbase + (size_t)scand * KW + sseg * 16;
    r0 = *(const bf16x8*)src;
    r1 = *(const bf16x8*)(src + 8);
    *(bf16x8*)&cbuf[0][scand * CST + sseg * 16]     = r0;
    *(bf16x8*)&cbuf[0][scand * CST + sseg * 16 + 8] = r1;
  } else {
    r2 = *(const ushort4*)(sbase + (size_t)scand * KW + sseg * 4);
    *(ushort4*)&cbuf[0][scand * CST + sseg * 4] = r2;
  }
  if (threadIdx.x < 32) cd2b[0][threadIdx.x] = d2base[threadIdx.x];
  __syncthreads();

#pragma unroll 1
  for (int ch = 0; ch < NCH; ++ch) {
    int cur = ch & 1;
    if (ch < NCH - 1) {   // issue next chunk's global loads early
      if constexpr (KW == 128) {
        const unsigned short* src = sbase + (size_t)(32 * (ch + 1) + scand) * KW + sseg * 16;
        r0 = *(const bf16x8*)src;
        r1 = *(const bf16x8*)(src + 8);
      } else {
        r2 = *(const ushort4*)(sbase + (size_t)(32 * (ch + 1) + scand) * KW + sseg * 4);
      }
      if (threadIdx.x < 32) rd2 = d2base[32 * (ch + 1) + threadIdx.x];
    }

    f32x4 acc0 = (f32x4){0.f, 0.f, 0.f, 0.f};
    f32x4 acc1 = (f32x4){0.f, 0.f, 0.f, 0.f};
    if constexpr (KW == 128) {
      // each cbuf b128 word feeds BOTH pairings (p0: af[j], p1: af[(j+2)&3])
      // -> 8 ds_read_b128 instead of 16
#pragma unroll
      for (int j = 0; j < 4; ++j) {
        int koff = j * 32 + lg * 8;
        bf16x8 a0 = *(const bf16x8*)&cbuf[cur][l15 * CST + koff];
        bf16x8 a1 = *(const bf16x8*)&cbuf[cur][(16 + l15) * CST + koff];
        acc0 = __builtin_amdgcn_mfma_f32_16x16x32_bf16(a0, af[j], acc0, 0, 0, 0);
        acc0 = __builtin_amdgcn_mfma_f32_16x16x32_bf16(a0, af[(j + 2) & 3], acc0, 0, 0, 0);
        acc1 = __builtin_amdgcn_mfma_f32_16x16x32_bf16(a1, af[j], acc1, 0, 0, 0);
        acc1 = __builtin_amdgcn_mfma_f32_16x16x32_bf16(a1, af[(j + 2) & 3], acc1, 0, 0, 0);
      }
    } else {
      bf16x8 a0 = *(const bf16x8*)&cbuf[cur][l15 * CST + lg * 8];
      bf16x8 a1 = *(const bf16x8*)&cbuf[cur][(16 + l15) * CST + lg * 8];
      acc0 = __builtin_amdgcn_mfma_f32_16x16x32_bf16(a0, af[0], acc0, 0, 0, 0);
      acc1 = __builtin_amdgcn_mfma_f32_16x16x32_bf16(a1, af[0], acc1, 0, 0, 0);
    }

    int cb = s * CS + ch * 32;
#pragma unroll
    for (int t = 0; t < 2; ++t) {
      f32x4 cd4 = *(const f32x4*)&cd2b[cur][t * 16 + lg * 4];
      f32x4 ac = t ? acc1 : acc0;
#pragma unroll
      for (int r = 0; r < 4; ++r) {
        float dist = fmaxf(fmaf(-2.f, ac[r], d2q + cd4[r]), 0.f);
        unsigned key = (__float_as_uint(dist) & 0xFFFFF000u)
                     | (unsigned)(cb + t * 16 + lg * 4 + r);
        // unconditional sorted-insert: identity when key >= bd[19]
#pragma unroll
        for (int t_ = KNN - 1; t_ >= 1; --t_) bd[t_] = umed3(key, bd[t_ - 1], bd[t_]);
        bd[0] = umn(bd[0], key);
      }
    }

    if (ch < NCH - 1) {
      if constexpr (KW == 128) {
        *(bf16x8*)&cbuf[cur ^ 1][scand * CST + sseg * 16]     = r0;
        *(bf16x8*)&cbuf[cur ^ 1][scand * CST + sseg * 16 + 8] = r1;
      } else {
        *(ushort4*)&cbuf[cur ^ 1][scand * CST + sseg * 4] = r2;
      }
      if (threadIdx.x < 32) cd2b[cur ^ 1][threadIdx.x] = rd2;
    }
    __syncthreads();
  }

  // merge 4 per-lane sorted lists via shuffles into lg==0 lanes (exact union)
#pragma unroll 1
  for (int li = 1; li < 4; ++li) {
#pragma unroll 1
    for (int k = 0; k < KNN; ++k) {
      unsigned v = __shfl(bd[k], l15 + li * 16, 64);
      if (lg == 0 && v < bd[KNN - 1]) {
#pragma unroll
        for (int t_ = KNN - 1; t_ >= 1; --t_) bd[t_] = umed3(v, bd[t_ - 1], bd[t_]);
        bd[0] = umn(bd[0], v);
      }
    }
  }
  if (lg == 0) {
    unsigned* dst = pdu + ((size_t)(b * NPTS + qloc + wv * 16 + l15) * S + s) * KNN;
#pragma unroll
    for (int k = 0; k < KNN; ++k) dst[k] = bd[k];
  }
}

// ---------------- merge S sorted packed-key lists -> idx ----------------
template<int S>
__global__ __launch_bounds__(256) void knn_mergek_kernel(
    const unsigned* __restrict__ pdu, int* __restrict__ idx) {
  int n = blockIdx.x * 256 + threadIdx.x;
  const unsigned* l0 = pdu + (size_t)n * S * KNN;
  unsigned bd[KNN];
#pragma unroll
  for (int k = 0; k < KNN; ++k) bd[k] = l0[k];
#pragma unroll 1
  for (int s = 1; s < S; ++s) {
#pragma unroll 1
    for (int k = 0; k < KNN; ++k) {
      unsigned v = l0[s * KNN + k];
      if (!(v < bd[KNN - 1])) break;   // source sorted ascending
#pragma unroll
      for (int t_ = KNN - 1; t_ >= 1; --t_) bd[t_] = umed3(v, bd[t_ - 1], bd[t_]);
      bd[0] = umn(bd[0], v);
    }
  }
#pragma unroll
  for (int k = 0; k < KNN; ++k) idx[(size_t)n * KNN + k] = (int)(bd[k] & 0xFFFu);
}

// ---------------- EdgeConv0: P,Q projections (D=3) ----------------
__global__ __launch_bounds__(256) void pq0_kernel(
    const float* __restrict__ x,
    const float* __restrict__ Wt, const float* __restrict__ bt,
    const float* __restrict__ Wp, const float* __restrict__ bp,
    float* __restrict__ P0, float* __restrict__ Q0) {
  int t = blockIdx.x * 256 + threadIdx.x;   // over BN*64
  int c = t & 63, n = t >> 6;
  const float* xr = x + (size_t)n * 3;
  float x0 = xr[0], x1 = xr[1], x2 = xr[2];
  float wt0 = Wt[0 * 64 + c], wt1 = Wt[1 * 64 + c], wt2 = Wt[2 * 64 + c];
  float wp0 = Wp[0 * 64 + c], wp1 = Wp[1 * 64 + c], wp2 = Wp[2 * 64 + c];
  P0[t] = x0 * wt0 + x1 * wt1 + x2 * wt2 + bt[c] + bp[c];
  Q0[t] = x0 * (wp0 - wt0) + x1 * (wp1 - wt1) + x2 * (wp2 - wt2);
}

// ---------------- BN batch stats over (B,N,K) ----------------
template<int C, int PB>
__global__ __launch_bounds__(256) void bn_stats_kernel(
    const float* __restrict__ P, const float* __restrict__ Q,
    const int* __restrict__ idx, float* __restrict__ stats /*[2][C]*/) {
  constexpr int G = 256 / C;
  int c = threadIdx.x % C;
  int g = threadIdx.x / C;
  int p0 = blockIdx.x * PB;
  float sum = 0.f, sq = 0.f;
  for (int p = g; p < PB; p += G) {
    int n = p0 + p;
    int b = n >> 12;
    float pc = P[(size_t)n * C + c];
    const int* id = idx + (size_t)n * KNN;
#pragma unroll
    for (int k = 0; k < KNN; ++k) {
      int j = id[k];
      float v = pc + Q[((size_t)(b << 12) + j) * C + c];
      sum += v; sq += v * v;
    }
  }
  if constexpr (G > 1) {
    __shared__ float ls[2][256];
    ls[0][threadIdx.x] = sum; ls[1][threadIdx.x] = sq;
    __syncthreads();
    if (g == 0) {
#pragma unroll
      for (int gg = 1; gg < G; ++gg) { sum += ls[0][gg * C + c]; sq += ls[1][gg * C + c]; }
      atomicAdd(&stats[c], sum); atomicAdd(&stats[C + c], sq);
    }
  } else {
    atomicAdd(&stats[c], sum); atomicAdd(&stats[C + c], sq);
  }
}

template<int C>
__global__ void bn_final_kernel(const float* __restrict__ stats,
                                const float* __restrict__ gamma,
                                const float* __restrict__ beta,
                                float* __restrict__ ss /*[2][C]*/) {
  int c = threadIdx.x;
  if (c < C) {
    const float cnt = (float)((size_t)BN * KNN);
    float mu  = stats[c] / cnt;
    float var = stats[C + c] / cnt - mu * mu;
    float sc  = gamma[c] * rsqrtf(var + BN_EPS);
    ss[c] = sc;
    ss[C + c] = beta[c] - mu * sc;
  }
}

// max over K (min if scale<0), affine, leaky-relu
template<int C, int PB>
__global__ __launch_bounds__(256) void bn_max_kernel(
    const float* __restrict__ P, const float* __restrict__ Q,
    const int* __restrict__ idx, const float* __restrict__ ss,
    float* __restrict__ hout) {
  constexpr int G = 256 / C;
  int c = threadIdx.x % C;
  int g = threadIdx.x / C;
  int p0 = blockIdx.x * PB;
  float sc = ss[c], sh = ss[C + c];
  for (int p = g; p < PB; p += G) {
    int n = p0 + p;
    int b = n >> 12;
    float pc = P[(size_t)n * C + c];
    const int* id = idx + (size_t)n * KNN;
    float vmax = -FINF, vmin = FINF;
#pragma unroll
    for (int k = 0; k < KNN; ++k) {
      int j = id[k];
      float v = pc + Q[((size_t)(b << 12) + j) * C + c];
      vmax = fmaxf(vmax, v); vmin = fminf(vmin, v);
    }
    float m = (sc >= 0.f) ? vmax : vmin;
    float y = m * sc + sh;
    hout[(size_t)n * C + c] = (y >= 0.f) ? y : SLOPE * y;
  }
}

// ---------------- EdgeConv1 projections: [BN,64]@[64,256] dual GEMM ----------------
__global__ __launch_bounds__(256) void pq1_kernel(
    const float* __restrict__ h0,
    const float* __restrict__ Wt, const float* __restrict__ bt,
    const float* __restrict__ Wp, const float* __restrict__ bp,
    float* __restrict__ P1, float* __restrict__ Q1) {
  __shared__ float hs[32][64];
  int r0 = blockIdx.x * 32;
  int cg = threadIdx.x & 63;     // cols cg*4 .. cg*4+3
  int wg = threadIdx.x >> 6;     // rows wg*8 .. wg*8+7
  for (int e = threadIdx.x; e < 512; e += 256)
    ((float4*)&hs[0][0])[e] = ((const float4*)(h0 + (size_t)r0 * 64))[e];
  __syncthreads();
  float accP[8][4] = {}, accQ[8][4] = {};
#pragma unroll 4
  for (int d = 0; d < 64; ++d) {
    float4 wt = *(const float4*)&Wt[d * 256 + cg * 4];
    float4 wp = *(const float4*)&Wp[d * 256 + cg * 4];
    float wdx = wp.x - wt.x, wdy = wp.y - wt.y, wdz = wp.z - wt.z, wdw = wp.w - wt.w;
#pragma unroll
    for (int rr = 0; rr < 8; ++rr) {
      float hv = hs[wg * 8 + rr][d];
      accP[rr][0] += hv * wt.x; accP[rr][1] += hv * wt.y;
      accP[rr][2] += hv * wt.z; accP[rr][3] += hv * wt.w;
      accQ[rr][0] += hv * wdx;  accQ[rr][1] += hv * wdy;
      accQ[rr][2] += hv * wdz;  accQ[rr][3] += hv * wdw;
    }
  }
  float4 b1 = *(const float4*)&bt[cg * 4];
  float4 b2 = *(const float4*)&bp[cg * 4];
  float bx = b1.x + b2.x, by = b1.y + b2.y, bz = b1.z + b2.z, bw = b1.w + b2.w;
#pragma unroll
  for (int rr = 0; rr < 8; ++rr) {
    size_t o = ((size_t)(r0 + wg * 8 + rr)) * 256 + cg * 4;
    *(float4*)&P1[o] = make_float4(accP[rr][0] + bx, accP[rr][1] + by,
                                   accP[rr][2] + bz, accP[rr][3] + bw);
    *(float4*)&Q1[o] = make_float4(accQ[rr][0], accQ[rr][1], accQ[rr][2], accQ[rr][3]);
  }
}

// ---------------- gate = relu(h1 @ Wg + bg) ----------------
__global__ __launch_bounds__(256) void gate_kernel(
    const float* __restrict__ h1, const float* __restrict__ Wg,
    const float* __restrict__ bg, float* __restrict__ gate) {
  int lane = threadIdx.x & 63;
  int n = blockIdx.x * 4 + (threadIdx.x >> 6);
  float4 a = ((const float4*)(h1 + (size_t)n * 256))[lane];
  float4 w = ((const float4*)Wg)[lane];
  float s = a.x * w.x + a.y * w.y + a.z * w.z + a.w * w.w;
#pragma unroll
  for (int off = 32; off >= 1; off >>= 1) s += __shfl_down(s, off);
  if (lane == 0) gate[n] = fmaxf(s + bg[0], 0.f);
}

// ---------------- softmax over N per batch ----------------
__global__ void softmax_kernel(const float* __restrict__ gate,
                               float* __restrict__ alpha) {
  __shared__ float red[256];
  int b = blockIdx.x;
  const float* g = gate + (size_t)b * NPTS;
  float* a = alpha + (size_t)b * NPTS;
  float m = -FINF;
  for (int i = threadIdx.x; i < NPTS; i += 256) m = fmaxf(m, g[i]);
  red[threadIdx.x] = m; __syncthreads();
  for (int st = 128; st >= 1; st >>= 1) {
    if (threadIdx.x < st) red[threadIdx.x] = fmaxf(red[threadIdx.x], red[threadIdx.x + st]);
    __syncthreads();
  }
  m = red[0]; __syncthreads();
  float s = 0.f;
  for (int i = threadIdx.x; i < NPTS; i += 256) s += expf(g[i] - m);
  red[threadIdx.x] = s; __syncthreads();
  for (int st = 128; st >= 1; st >>= 1) {
    if (threadIdx.x < st) red[threadIdx.x] += red[threadIdx.x + st];
    __syncthreads();
  }
  float inv = 1.f / red[0];
  for (int i = threadIdx.x; i < NPTS; i += 256) a[i] = expf(g[i] - m) * inv;
}

// ---------------- feat GEMM fused with relu + alpha-weighted pooling ----------------
__global__ __launch_bounds__(256) void featpool_kernel(
    const float* __restrict__ h1, const float* __restrict__ Wf,
    const float* __restrict__ bf, const float* __restrict__ alpha,
    float* __restrict__ pooled) {
  __shared__ float As[64][40];
  __shared__ float Bs[32][68];
  __shared__ float Rs[16][64];
  int bid = blockIdx.x;
  int ot = bid & 7;
  int nt = (bid >> 3) & 63;
  int b  = bid >> 9;
  int o0 = ot * 64;
  int n0 = nt * 64;
  int og = threadIdx.x & 15;
  int ng = threadIdx.x >> 4;
  float acc[4][4] = {};
  for (int ct = 0; ct < 8; ++ct) {
    __syncthreads();
    {
      int e = threadIdx.x;
#pragma unroll
      for (int it = 0; it < 2; ++it, e += 256) {
        int row = e >> 3, c4 = e & 7;
        float4 v = *(const float4*)&h1[((size_t)(b * NPTS + n0 + row)) * 256 + ct * 32 + c4 * 4];
        *(float4*)&As[row][c4 * 4] = v;
      }
    }
    {
      int e = threadIdx.x;
#pragma unroll
      for (int it = 0; it < 2; ++it, e += 256) {
        int row = e >> 4, c16 = e & 15;
        float4 v = *(const float4*)&Wf[((size_t)(ct * 32 + row)) * 512 + o0 + c16 * 4];
        *(float4*)&Bs[row][c16 * 4] = v;
      }
    }
    __syncthreads();
#pragma unroll
    for (int c4 = 0; c4 < 8; ++c4) {
      float4 av[4], bv[4];
#pragma unroll
      for (int u = 0; u < 4; ++u) av[u] = *(const float4*)&As[ng * 4 + u][c4 * 4];
#pragma unroll
      for (int u = 0; u < 4; ++u) bv[u] = *(const float4*)&Bs[c4 * 4 + u][og * 4];
#pragma unroll
      for (int nn = 0; nn < 4; ++nn) {
        float a0 = av[nn].x, a1 = av[nn].y, a2 = av[nn].z, a3 = av[nn].w;
        acc[nn][0] += a0 * bv[0].x + a1 * bv[1].x + a2 * bv[2].x + a3 * bv[3].x;
        acc[nn][1] += a0 * bv[0].y + a1 * bv[1].y + a2 * bv[2].y + a3 * bv[3].y;
        acc[nn][2] += a0 * bv[0].z + a1 * bv[1].z + a2 * bv[2].z + a3 * bv[3].z;
        acc[nn][3] += a0 * bv[0].w + a1 * bv[1].w + a2 * bv[2].w + a3 * bv[3].w;
      }
    }
  }
  float po[4] = {0.f, 0.f, 0.f, 0.f};
#pragma unroll
  for (int nn = 0; nn < 4; ++nn) {
    float al = alpha[(size_t)b * NPTS + n0 + ng * 4 + nn];
#pragma unroll
    for (int oo = 0; oo < 4; ++oo) {
      float f = acc[nn][oo] + bf[o0 + og * 4 + oo];
      f = fmaxf(f, 0.f);
      po[oo] += al * f;
    }
  }
  __syncthreads();
  *(float4*)&Rs[ng][og * 4] = make_float4(po[0], po[1], po[2], po[3]);
  __syncthreads();
  if (threadIdx.x < 64) {
    float s2 = 0.f;
#pragma unroll
    for (int gg = 0; gg < 16; ++gg) s2 += Rs[gg][threadIdx.x];
    atomicAdd(&pooled[(size_t)b * DF + o0 + threadIdx.x], s2);
  }
}

// ---------------- out = pooled @ Wl + bl ----------------
__global__ __launch_bounds__(256) void final_kernel(
    const float* __restrict__ pooled, const float* __restrict__ Wl,
    const float* __restrict__ bl, float* __restrict__ out) {
  __shared__ float ps[DF];
  int b = blockIdx.x, j = threadIdx.x;
  for (int e = threadIdx.x; e < DF; e += 256) ps[e] = pooled[(size_t)b * DF + e];
  __syncthreads();
  float a0 = 0.f, a1 = 0.f, a2 = 0.f, a3 = 0.f;
  for (int o = 0; o < DF; o += 4) {
    a0 += ps[o + 0] * Wl[(size_t)(o + 0) * DOUT + j];
    a1 += ps[o + 1] * Wl[(size_t)(o + 1) * DOUT + j];
    a2 += ps[o + 2] * Wl[(size_t)(o + 2) * DOUT + j];
    a3 += ps[o + 3] * Wl[(size_t)(o + 3) * DOUT + j];
  }
  out[(size_t)b * DOUT + j] = (a0 + a1) + (a2 + a3) + bl[j];
}

// ---------------- launch ----------------
extern "C" void kernel_launch(void* const* d_in, const int* in_sizes, int n_in,
                              void* d_out, int out_size, void* d_ws, size_t ws_size,
                              hipStream_t stream) {
  (void)in_sizes; (void)n_in; (void)out_size; (void)ws_size;
  const float* x   = (const float*)d_in[0];
  const float* Wt0 = (const float*)d_in[1];
  const float* bt0 = (const float*)d_in[2];
  const float* Wp0 = (const float*)d_in[3];
  const float* bp0 = (const float*)d_in[4];
  const float* g0  = (const float*)d_in[5];
  const float* be0 = (const float*)d_in[6];
  const float* Wt1 = (const float*)d_in[7];
  const float* bt1 = (const float*)d_in[8];
  const float* Wp1 = (const float*)d_in[9];
  const float* bp1 = (const float*)d_in[10];
  const float* g1  = (const float*)d_in[11];
  const float* be1 = (const float*)d_in[12];
  const float* Wg  = (const float*)d_in[13];
  const float* bg  = (const float*)d_in[14];
  const float* Wf  = (const float*)d_in[15];
  const float* bf  = (const float*)d_in[16];
  const float* Wl  = (const float*)d_in[17];
  const float* bl  = (const float*)d_in[18];
  float* out = (float*)d_out;
  char* ws = (char*)d_ws;

  float* H0     = (float*)(ws + OFF_H0);
  int*   IDX0   = (int*)  (ws + OFF_IDX0);
  int*   IDX1   = (int*)  (ws + OFF_IDX1);
  float* D2     = (float*)(ws + OFF_D2);
  float* GATE   = (float*)(ws + OFF_GATE);
  float* ALPHA  = (float*)(ws + OFF_ALPHA);
  float* SS0    = (float*)(ws + OFF_SS0);
  float* SS1    = (float*)(ws + OFF_SS1);
  float* STATS0 = (float*)(ws + OFF_STATS0);
  float* STATS1 = (float*)(ws + OFF_STATS1);
  float* POOLED = (float*)(ws + OFF_POOLED);
  float* P1     = (float*)(ws + OFF_P1);
  float* Q1     = (float*)(ws + OFF_Q1);
  float* H1     = (float*)(ws + OFF_H1);
  float* P0     = (float*)(ws + OFF_P0);
  float* Q0     = (float*)(ws + OFF_Q0);
  unsigned short* AB = (unsigned short*)(ws + OFF_AB);
  unsigned* PDU = (unsigned*)(ws + OFF_PDU);
  unsigned short* U0 = (unsigned short*)(ws + OFF_U0);
  unsigned short* V0 = (unsigned short*)(ws + OFF_V0);

  hipMemsetAsync(ws + ZERO_OFF, 0, ZERO_BYTES, stream);

  // ----- layer 0: knn on xyz (MFMA packed split), EdgeConv 3->64 -----
  d2_kernel<3><<<BN / 256, 256, 0, stream>>>(x, D2);
  usplit0_kernel<<<BN / 256, 256, 0, stream>>>(x, U0, V0);
  knn_mfsel_kernel<32, 40, 8><<<(BN / 64) * 8, 256, 0, stream>>>(V0, U0, D2, PDU);
  knn_mergek_kernel<8><<<BN / 256, 256, 0, stream>>>(PDU, IDX0);
  pq0_kernel<<<BN * 64 / 256, 256, 0, stream>>>(x, Wt0, bt0, Wp0, bp0, P0, Q0);
  bn_stats_kernel<64, 32><<<BN / 32, 256, 0, stream>>>(P0, Q0, IDX0, STATS0);
  bn_final_kernel<64><<<1, 64, 0, stream>>>(STATS0, g0, be0, SS0);
  bn_max_kernel<64, 32><<<BN / 32, 256, 0, stream>>>(P0, Q0, IDX0, SS0, H0);

  // ----- layer 1: knn on 64-d features (MFMA bf16-split), EdgeConv 64->256 -----
  d2_kernel<64><<<BN / 256, 256, 0, stream>>>(H0, D2);
  split_kernel<<<BN * 16 / 256, 256, 0, stream>>>(H0, AB);
  knn_mfsel_kernel<128, 136, 8><<<(BN / 64) * 8, 256, 0, stream>>>(AB, AB, D2, PDU);
  knn_mergek_kernel<8><<<BN / 256, 256, 0, stream>>>(PDU, IDX1);
  pq1_kernel<<<BN / 32, 256, 0, stream>>>(H0, Wt1, bt1, Wp1, bp1, P1, Q1);
  bn_stats_kernel<256, 16><<<BN / 16, 256, 0, stream>>>(P1, Q1, IDX1, STATS1);
  bn_final_kernel<256><<<1, 256, 0, stream>>>(STATS1, g1, be1, SS1);
  bn_max_kernel<256, 16><<<BN / 16, 256, 0, stream>>>(P1, Q1, IDX1, SS1, H1);

  // ----- attention pooling + final linear -----
  gate_kernel<<<BN / 4, 256, 0, stream>>>(H1, Wg, bg, GATE);
  softmax_kernel<<<NBATCH, 256, 0, stream>>>(GATE, ALPHA);
  featpool_kernel<<<NBATCH * 64 * 8, 256, 0, stream>>>(H1, Wf, bf, ALPHA, POOLED);
  final_kernel<<<NBATCH, 256, 0, stream>>>(POOLED, Wl, bl, out);
}

// Round 7
// 484.237 us; speedup vs baseline: 1.1462x; 1.1462x over previous
//
#include <hip/hip_runtime.h>
#include <hip/hip_bf16.h>
#include <math.h>

// ---------------- problem constants ----------------
static constexpr int NBATCH = 4;
static constexpr int NPTS   = 4096;
static constexpr int BN     = NBATCH * NPTS;   // 16384
static constexpr int KNN    = 20;
static constexpr float BN_EPS = 1e-5f;
static constexpr float SLOPE  = 0.2f;
static constexpr int C0 = 64, C1 = 256, DF = 512, DOUT = 256;

#define FINF __builtin_huge_valf()

typedef short bf16x8 __attribute__((ext_vector_type(8)));
typedef float f32x4  __attribute__((ext_vector_type(4)));

// ---------------- workspace layout (bytes) ----------------
// H0/VMM0 share [0,4MB): bn_gather0 writes VMM0, apply0 rewrites H0 in place.
// H1/VMM1 share [44.8,61.6MB): same in-place pattern.
static constexpr size_t OFF_H0     = 0;                    // 4 MB (VMM0 then H0)
static constexpr size_t OFF_IDX0   = 4194304;              // 1.25 MB
static constexpr size_t OFF_IDX1   = 5505024;              // 1.25 MB
static constexpr size_t OFF_D2     = 6815744;              // 64 KB
static constexpr size_t OFF_GATE   = 6881280;              // 64 KB
static constexpr size_t OFF_ALPHA  = 6946816;              // 64 KB
static constexpr size_t OFF_SS0    = 7012352;
static constexpr size_t OFF_SS1    = 7012864;
static constexpr size_t OFF_STATS0 = 7014912;
static constexpr size_t OFF_STATS1 = 7015424;
static constexpr size_t OFF_POOLED = 7017472;              // -> end 7,025,664
static constexpr size_t ZERO_OFF   = OFF_STATS0;
static constexpr size_t ZERO_BYTES = 7025664 - 7014912;
static constexpr size_t OFF_P1     = 7025664;              // 16 MB (pq1 output; earlier: PDU)
static constexpr size_t OFF_PDU    = OFF_P1;               // S=4: 16384*4*20*4 = 5.24 MB
static constexpr size_t OFF_Q1     = 27997184;             // 16 MB (pq1 output; earlier: U0/V0, P0/Q0)
static constexpr size_t OFF_U0     = OFF_Q1;               // 1 MB
static constexpr size_t OFF_V0     = OFF_Q1 + 1048576;     // 1 MB
static constexpr size_t OFF_P0     = OFF_Q1;               // 4 MB (after knn0 consumed U0/V0)
static constexpr size_t OFF_Q0     = OFF_Q1 + 4194304;     // 4 MB
static constexpr size_t OFF_H1     = 44774400;             // 16 MB (VMM1 then H1) -> end 61,551,616
static constexpr size_t OFF_AB     = 61551616;             // 4 MB -> end 65,745,920

// ---------------- helpers ----------------
__device__ inline unsigned short f2bf_rne(float x) {
  unsigned int u = __float_as_uint(x);
  unsigned int lsb = (u >> 16) & 1u;
  u += 0x7fffu + lsb;
  return (unsigned short)(u >> 16);
}
__device__ inline float bf2f(unsigned short s) {
  return __uint_as_float((unsigned int)s << 16);
}
__device__ inline unsigned umn(unsigned a, unsigned b) { return a < b ? a : b; }
// clamp(v, lo, hi) with lo<=hi == sorted-insert slot update, single instr.
// When v >= hi the result is hi (identity) -> insert runs UNCONDITIONALLY.
__device__ inline unsigned umed3(unsigned v, unsigned lo, unsigned hi) {
  unsigned d;
  asm("v_med3_u32 %0, %1, %2, %3" : "=v"(d) : "v"(v), "v"(lo), "v"(hi));
  return d;
}

// ---------------- d2 = sum(x*x), D=3 ----------------
__global__ __launch_bounds__(256) void d2x_kernel(const float* __restrict__ x,
                                                  float* __restrict__ d2) {
  int n = blockIdx.x * 256 + threadIdx.x;
  const float* r = x + (size_t)n * 3;
  d2[n] = r[0] * r[0] + r[1] * r[1] + r[2] * r[2];
}

// ---------------- layer-0 packing: U=[A,B,A,B,0..] (queries), V=[A,A,B,B,0..] (cands) ------
// dot(U_q, V_c) = Aq.Ac + Bq.Ac + Aq.Bc + Bq.Bc = exact (Aq+Bq).(Ac+Bc)
__global__ __launch_bounds__(256) void usplit0_kernel(
    const float* __restrict__ x, unsigned short* __restrict__ U0,
    unsigned short* __restrict__ V0) {
  int n = blockIdx.x * 256 + threadIdx.x;
  float v0 = x[(size_t)n * 3], v1 = x[(size_t)n * 3 + 1], v2 = x[(size_t)n * 3 + 2];
  unsigned short A0 = f2bf_rne(v0), A1 = f2bf_rne(v1), A2 = f2bf_rne(v2);
  unsigned short B0 = f2bf_rne(v0 - bf2f(A0));
  unsigned short B1 = f2bf_rne(v1 - bf2f(A1));
  unsigned short B2 = f2bf_rne(v2 - bf2f(A2));
  ushort4 z = make_ushort4(0, 0, 0, 0);
  unsigned short* up = U0 + ((size_t)n << 5);
  ((ushort4*)up)[0] = make_ushort4(A0, A1, A2, B0);
  ((ushort4*)up)[1] = make_ushort4(B1, B2, A0, A1);
  ((ushort4*)up)[2] = make_ushort4(A2, B0, B1, B2);
  ((ushort4*)up)[3] = z; ((ushort4*)up)[4] = z; ((ushort4*)up)[5] = z;
  ((ushort4*)up)[6] = z; ((ushort4*)up)[7] = z;
  unsigned short* vp = V0 + ((size_t)n << 5);
  ((ushort4*)vp)[0] = make_ushort4(A0, A1, A2, A0);
  ((ushort4*)vp)[1] = make_ushort4(A1, A2, B0, B1);
  ((ushort4*)vp)[2] = make_ushort4(B2, B0, B1, B2);
  ((ushort4*)vp)[3] = z; ((ushort4*)vp)[4] = z; ((ushort4*)vp)[5] = z;
  ((ushort4*)vp)[6] = z; ((ushort4*)vp)[7] = z;
}

// ---------------- unified MFMA KNN with in-register selection ----------------
// block = 4 waves, 64 queries (16/wave); candidate split S (grid BN/64*S);
// operand-swapped MFMA: D[cand][query] -> lane (l15,lg) holds 8 cands of query l15.
// key = (dist_bits & 0xFFFFF000) | idx12; UNCONDITIONAL med3 cascade;
// per-lane lists merged via __shfl into lg==0 (union superset -> exact top-20).
// launch_bounds(256,4): 4 waves/EU -> 128 VGPR budget, no scratch spills.
template<int KW, int CST, int S>
__global__ __launch_bounds__(256, 4) void knn_mfsel_kernel(
    const unsigned short* __restrict__ cab,   // candidate rows [BN][KW]
    const unsigned short* __restrict__ qab,   // query rows [BN][KW]
    const float* __restrict__ d2,
    unsigned* __restrict__ pdu) {
  constexpr int CS = NPTS / S, NCH = CS / 32;
  __shared__ __align__(16) unsigned short cbuf[2][32 * CST];
  __shared__ __align__(16) float cd2b[2][32];

  int bid = blockIdx.x;
  int s   = bid & (S - 1);
  int qb  = bid / S;
  int b   = qb >> 6;
  int qloc = (qb & 63) * 64;
  int wv = threadIdx.x >> 6, lane = threadIdx.x & 63;
  int l15 = lane & 15, lg = lane >> 4;
  int qg = b * NPTS + qloc + wv * 16 + l15;   // this lane's query row

  bf16x8 af[KW / 32];
#pragma unroll
  for (int kk = 0; kk < KW / 32; ++kk)
    af[kk] = *(const bf16x8*)(qab + (size_t)qg * KW + kk * 32 + lg * 8);
  float d2q = d2[qg];

  unsigned bd[KNN];
#pragma unroll
  for (int k = 0; k < KNN; ++k) bd[k] = 0xFFFFFFFFu;

  int scand = threadIdx.x >> 3, sseg = threadIdx.x & 7;
  const unsigned short* sbase = cab + ((size_t)(b * NPTS + s * CS)) * KW;
  const float* d2base = d2 + b * NPTS + s * CS;

  bf16x8 r0, r1;
  ushort4 r2;
  float rd2 = 0.f;

  // prologue: chunk 0
  if constexpr (KW == 128) {
    const unsigned short* src = sbase + (size_t)scand * KW + sseg * 16;
    r0 = *(const bf16x8*)src;
    r1 = *(const bf16x8*)(src + 8);
    *(bf16x8*)&cbuf[0][scand * CST + sseg * 16]     = r0;
    *(bf16x8*)&cbuf[0][scand * CST + sseg * 16 + 8] = r1;
  } else {
    r2 = *(const ushort4*)(sbase + (size_t)scand * KW + sseg * 4);
    *(ushort4*)&cbuf[0][scand * CST + sseg * 4] = r2;
  }
  if (threadIdx.x < 32) cd2b[0][threadIdx.x] = d2base[threadIdx.x];
  __syncthreads();

#pragma unroll 1
  for (int ch = 0; ch < NCH; ++ch) {
    int cur = ch & 1;
    if (ch < NCH - 1) {   // issue next chunk's global loads early
      if constexpr (KW == 128) {
        const unsigned short* src = sbase + (size_t)(32 * (ch + 1) + scand) * KW + sseg * 16;
        r0 = *(const bf16x8*)src;
        r1 = *(const bf16x8*)(src + 8);
      } else {
        r2 = *(const ushort4*)(sbase + (size_t)(32 * (ch + 1) + scand) * KW + sseg * 4);
      }
      if (threadIdx.x < 32) rd2 = d2base[32 * (ch + 1) + threadIdx.x];
    }

    f32x4 acc0 = (f32x4){0.f, 0.f, 0.f, 0.f};
    f32x4 acc1 = (f32x4){0.f, 0.f, 0.f, 0.f};
    if constexpr (KW == 128) {
      // each cbuf b128 word feeds BOTH split pairings -> 8 ds_read_b128
#pragma unroll
      for (int j = 0; j < 4; ++j) {
        int koff = j * 32 + lg * 8;
        bf16x8 a0 = *(const bf16x8*)&cbuf[cur][l15 * CST + koff];
        bf16x8 a1 = *(const bf16x8*)&cbuf[cur][(16 + l15) * CST + koff];
        acc0 = __builtin_amdgcn_mfma_f32_16x16x32_bf16(a0, af[j], acc0, 0, 0, 0);
        acc0 = __builtin_amdgcn_mfma_f32_16x16x32_bf16(a0, af[(j + 2) & 3], acc0, 0, 0, 0);
        acc1 = __builtin_amdgcn_mfma_f32_16x16x32_bf16(a1, af[j], acc1, 0, 0, 0);
        acc1 = __builtin_amdgcn_mfma_f32_16x16x32_bf16(a1, af[(j + 2) & 3], acc1, 0, 0, 0);
      }
    } else {
      bf16x8 a0 = *(const bf16x8*)&cbuf[cur][l15 * CST + lg * 8];
      bf16x8 a1 = *(const bf16x8*)&cbuf[cur][(16 + l15) * CST + lg * 8];
      acc0 = __builtin_amdgcn_mfma_f32_16x16x32_bf16(a0, af[0], acc0, 0, 0, 0);
      acc1 = __builtin_amdgcn_mfma_f32_16x16x32_bf16(a1, af[0], acc1, 0, 0, 0);
    }

    int cb = s * CS + ch * 32;
#pragma unroll
    for (int t = 0; t < 2; ++t) {
      f32x4 cd4 = *(const f32x4*)&cd2b[cur][t * 16 + lg * 4];
      f32x4 ac = t ? acc1 : acc0;
#pragma unroll
      for (int r = 0; r < 4; ++r) {
        float dist = fmaxf(fmaf(-2.f, ac[r], d2q + cd4[r]), 0.f);
        unsigned key = (__float_as_uint(dist) & 0xFFFFF000u)
                     | (unsigned)(cb + t * 16 + lg * 4 + r);
#pragma unroll
        for (int t_ = KNN - 1; t_ >= 1; --t_) bd[t_] = umed3(key, bd[t_ - 1], bd[t_]);
        bd[0] = umn(bd[0], key);
      }
    }

    if (ch < NCH - 1) {
      if constexpr (KW == 128) {
        *(bf16x8*)&cbuf[cur ^ 1][scand * CST + sseg * 16]     = r0;
        *(bf16x8*)&cbuf[cur ^ 1][scand * CST + sseg * 16 + 8] = r1;
      } else {
        *(ushort4*)&cbuf[cur ^ 1][scand * CST + sseg * 4] = r2;
      }
      if (threadIdx.x < 32) cd2b[cur ^ 1][threadIdx.x] = rd2;
    }
    __syncthreads();
  }

  // merge 4 per-lane sorted lists via shuffles into lg==0 lanes (exact union)
#pragma unroll 1
  for (int li = 1; li < 4; ++li) {
#pragma unroll 1
    for (int k = 0; k < KNN; ++k) {
      unsigned v = __shfl(bd[k], l15 + li * 16, 64);
      if (lg == 0 && v < bd[KNN - 1]) {
#pragma unroll
        for (int t_ = KNN - 1; t_ >= 1; --t_) bd[t_] = umed3(v, bd[t_ - 1], bd[t_]);
        bd[0] = umn(bd[0], v);
      }
    }
  }
  if (lg == 0) {
    unsigned* dst = pdu + ((size_t)(b * NPTS + qloc + wv * 16 + l15) * S + s) * KNN;
#pragma unroll
    for (int k = 0; k < KNN; ++k) dst[k] = bd[k];
  }
}

// ---------------- merge S sorted packed-key lists -> idx ----------------
template<int S>
__global__ __launch_bounds__(256) void knn_mergek_kernel(
    const unsigned* __restrict__ pdu, int* __restrict__ idx) {
  int n = blockIdx.x * 256 + threadIdx.x;
  const unsigned* l0 = pdu + (size_t)n * S * KNN;
  unsigned bd[KNN];
#pragma unroll
  for (int k = 0; k < KNN; ++k) bd[k] = l0[k];
#pragma unroll 1
  for (int s = 1; s < S; ++s) {
#pragma unroll 1
    for (int k = 0; k < KNN; ++k) {
      unsigned v = l0[s * KNN + k];
      if (!(v < bd[KNN - 1])) break;   // source sorted ascending
#pragma unroll
      for (int t_ = KNN - 1; t_ >= 1; --t_) bd[t_] = umed3(v, bd[t_ - 1], bd[t_]);
      bd[0] = umn(bd[0], v);
    }
  }
#pragma unroll
  for (int k = 0; k < KNN; ++k) idx[(size_t)n * KNN + k] = (int)(bd[k] & 0xFFFu);
}

// ---------------- EdgeConv0: P,Q projections (D=3) ----------------
__global__ __launch_bounds__(256) void pq0_kernel(
    const float* __restrict__ x,
    const float* __restrict__ Wt, const float* __restrict__ bt,
    const float* __restrict__ Wp, const float* __restrict__ bp,
    float* __restrict__ P0, float* __restrict__ Q0) {
  int t = blockIdx.x * 256 + threadIdx.x;   // over BN*64
  int c = t & 63, n = t >> 6;
  const float* xr = x + (size_t)n * 3;
  float x0 = xr[0], x1 = xr[1], x2 = xr[2];
  float wt0 = Wt[0 * 64 + c], wt1 = Wt[1 * 64 + c], wt2 = Wt[2 * 64 + c];
  float wp0 = Wp[0 * 64 + c], wp1 = Wp[1 * 64 + c], wp2 = Wp[2 * 64 + c];
  P0[t] = x0 * wt0 + x1 * wt1 + x2 * wt2 + bt[c] + bp[c];
  Q0[t] = x0 * (wp0 - wt0) + x1 * (wp1 - wt1) + x2 * (wp2 - wt2);
}

// ---------------- fused BN gather: stats (sum,sq) + per-(n,c) vmax/vmin ----------------
// Single gather pass. vmm[n*C+c] = (bf16(vmax)<<16) | bf16(vmin).
template<int C, int PB>
__global__ __launch_bounds__(256) void bn_gather_kernel(
    const float* __restrict__ P, const float* __restrict__ Q,
    const int* __restrict__ idx, float* __restrict__ stats /*[2][C]*/,
    unsigned* __restrict__ vmm) {
  constexpr int G = 256 / C;
  int c = threadIdx.x % C;
  int g = threadIdx.x / C;
  int p0 = blockIdx.x * PB;
  float sum = 0.f, sq = 0.f;
  for (int p = g; p < PB; p += G) {
    int n = p0 + p;
    int b = n >> 12;
    float pc = P[(size_t)n * C + c];
    const int* id = idx + (size_t)n * KNN;
    float vmax = -FINF, vmin = FINF;
#pragma unroll
    for (int k = 0; k < KNN; ++k) {
      int j = id[k];
      float v = pc + Q[((size_t)(b << 12) + j) * C + c];
      sum += v; sq += v * v;
      vmax = fmaxf(vmax, v); vmin = fminf(vmin, v);
    }
    vmm[(size_t)n * C + c] = ((unsigned)f2bf_rne(vmax) << 16) | f2bf_rne(vmin);
  }
  if constexpr (G > 1) {
    __shared__ float ls[2][256];
    ls[0][threadIdx.x] = sum; ls[1][threadIdx.x] = sq;
    __syncthreads();
    if (g == 0) {
#pragma unroll
      for (int gg = 1; gg < G; ++gg) { sum += ls[0][gg * C + c]; sq += ls[1][gg * C + c]; }
      atomicAdd(&stats[c], sum); atomicAdd(&stats[C + c], sq);
    }
  } else {
    atomicAdd(&stats[c], sum); atomicAdd(&stats[C + c], sq);
  }
}

template<int C>
__global__ void bn_final_kernel(const float* __restrict__ stats,
                                const float* __restrict__ gamma,
                                const float* __restrict__ beta,
                                float* __restrict__ ss /*[2][C]*/) {
  int c = threadIdx.x;
  if (c < C) {
    const float cnt = (float)((size_t)BN * KNN);
    float mu  = stats[c] / cnt;
    float var = stats[C + c] / cnt - mu * mu;
    float sc  = gamma[c] * rsqrtf(var + BN_EPS);
    ss[c] = sc;
    ss[C + c] = beta[c] - mu * sc;
  }
}

// ---------------- apply0: affine+lrelu from vmm0, emit H0 (in place), AB split, D2 ------
__global__ __launch_bounds__(256) void apply0_kernel(
    const unsigned* __restrict__ vmm, const float* __restrict__ ss,
    float* __restrict__ H0, unsigned short* __restrict__ ab,
    float* __restrict__ d2) {
  int wv = threadIdx.x >> 6, lane = threadIdx.x & 63;
  int n = blockIdx.x * 4 + wv;
  unsigned pk = vmm[(size_t)n * 64 + lane];
  float sc = ss[lane], sh = ss[64 + lane];
  float vmax = bf2f((unsigned short)(pk >> 16));
  float vmin = bf2f((unsigned short)(pk & 0xFFFFu));
  float m = (sc >= 0.f) ? vmax : vmin;
  float y = fmaf(m, sc, sh);
  y = (y >= 0.f) ? y : SLOPE * y;
  H0[(size_t)n * 64 + lane] = y;
  unsigned short a = f2bf_rne(y);
  unsigned short b = f2bf_rne(y - bf2f(a));
  ab[(size_t)n * 128 + lane] = a;
  ab[(size_t)n * 128 + 64 + lane] = b;
  float s = y * y;
#pragma unroll
  for (int off = 32; off >= 1; off >>= 1) s += __shfl_down(s, off);
  if (lane == 0) d2[n] = s;
}

// ---------------- apply1: affine+lrelu from vmm1, emit H1 (in place) + gate ----------
__global__ __launch_bounds__(256) void apply1_kernel(
    const unsigned* __restrict__ vmm, const float* __restrict__ ss,
    const float* __restrict__ Wg, const float* __restrict__ bg,
    float* __restrict__ H1, float* __restrict__ gate) {
  int wv = threadIdx.x >> 6, lane = threadIdx.x & 63;
  int n = blockIdx.x * 4 + wv;
  float gsum = 0.f;
#pragma unroll
  for (int i = 0; i < 4; ++i) {
    int c = lane + 64 * i;
    unsigned pk = vmm[(size_t)n * 256 + c];
    float sc = ss[c], sh = ss[256 + c];
    float vmax = bf2f((unsigned short)(pk >> 16));
    float vmin = bf2f((unsigned short)(pk & 0xFFFFu));
    float m = (sc >= 0.f) ? vmax : vmin;
    float y = fmaf(m, sc, sh);
    y = (y >= 0.f) ? y : SLOPE * y;
    H1[(size_t)n * 256 + c] = y;
    gsum += y * Wg[c];
  }
#pragma unroll
  for (int off = 32; off >= 1; off >>= 1) gsum += __shfl_down(gsum, off);
  if (lane == 0) gate[n] = fmaxf(gsum + bg[0], 0.f);
}

// ---------------- EdgeConv1 projections: [BN,64]@[64,256] dual GEMM ----------------
__global__ __launch_bounds__(256) void pq1_kernel(
    const float* __restrict__ h0,
    const float* __restrict__ Wt, const float* __restrict__ bt,
    const float* __restrict__ Wp, const float* __restrict__ bp,
    float* __restrict__ P1, float* __restrict__ Q1) {
  __shared__ float hs[32][64];
  int r0 = blockIdx.x * 32;
  int cg = threadIdx.x & 63;     // cols cg*4 .. cg*4+3
  int wg = threadIdx.x >> 6;     // rows wg*8 .. wg*8+7
  for (int e = threadIdx.x; e < 512; e += 256)
    ((float4*)&hs[0][0])[e] = ((const float4*)(h0 + (size_t)r0 * 64))[e];
  __syncthreads();
  float accP[8][4] = {}, accQ[8][4] = {};
#pragma unroll 4
  for (int d = 0; d < 64; ++d) {
    float4 wt = *(const float4*)&Wt[d * 256 + cg * 4];
    float4 wp = *(const float4*)&Wp[d * 256 + cg * 4];
    float wdx = wp.x - wt.x, wdy = wp.y - wt.y, wdz = wp.z - wt.z, wdw = wp.w - wt.w;
#pragma unroll
    for (int rr = 0; rr < 8; ++rr) {
      float hv = hs[wg * 8 + rr][d];
      accP[rr][0] += hv * wt.x; accP[rr][1] += hv * wt.y;
      accP[rr][2] += hv * wt.z; accP[rr][3] += hv * wt.w;
      accQ[rr][0] += hv * wdx;  accQ[rr][1] += hv * wdy;
      accQ[rr][2] += hv * wdz;  accQ[rr][3] += hv * wdw;
    }
  }
  float4 b1 = *(const float4*)&bt[cg * 4];
  float4 b2 = *(const float4*)&bp[cg * 4];
  float bx = b1.x + b2.x, by = b1.y + b2.y, bz = b1.z + b2.z, bw = b1.w + b2.w;
#pragma unroll
  for (int rr = 0; rr < 8; ++rr) {
    size_t o = ((size_t)(r0 + wg * 8 + rr)) * 256 + cg * 4;
    *(float4*)&P1[o] = make_float4(accP[rr][0] + bx, accP[rr][1] + by,
                                   accP[rr][2] + bz, accP[rr][3] + bw);
    *(float4*)&Q1[o] = make_float4(accQ[rr][0], accQ[rr][1], accQ[rr][2], accQ[rr][3]);
  }
}

// ---------------- softmax over N per batch ----------------
__global__ void softmax_kernel(const float* __restrict__ gate,
                               float* __restrict__ alpha) {
  __shared__ float red[256];
  int b = blockIdx.x;
  const float* g = gate + (size_t)b * NPTS;
  float* a = alpha + (size_t)b * NPTS;
  float m = -FINF;
  for (int i = threadIdx.x; i < NPTS; i += 256) m = fmaxf(m, g[i]);
  red[threadIdx.x] = m; __syncthreads();
  for (int st = 128; st >= 1; st >>= 1) {
    if (threadIdx.x < st) red[threadIdx.x] = fmaxf(red[threadIdx.x], red[threadIdx.x + st]);
    __syncthreads();
  }
  m = red[0]; __syncthreads();
  float s = 0.f;
  for (int i = threadIdx.x; i < NPTS; i += 256) s += expf(g[i] - m);
  red[threadIdx.x] = s; __syncthreads();
  for (int st = 128; st >= 1; st >>= 1) {
    if (threadIdx.x < st) red[threadIdx.x] += red[threadIdx.x + st];
    __syncthreads();
  }
  float inv = 1.f / red[0];
  for (int i = threadIdx.x; i < NPTS; i += 256) a[i] = expf(g[i] - m) * inv;
}

// ---------------- feat GEMM fused with relu + alpha-weighted pooling ----------------
__global__ __launch_bounds__(256) void featpool_kernel(
    const float* __restrict__ h1, const float* __restrict__ Wf,
    const float* __restrict__ bf, const float* __restrict__ alpha,
    float* __restrict__ pooled) {
  __shared__ float As[64][40];
  __shared__ float Bs[32][68];
  __shared__ float Rs[16][64];
  int bid = blockIdx.x;
  int ot = bid & 7;
  int nt = (bid >> 3) & 63;
  int b  = bid >> 9;
  int o0 = ot * 64;
  int n0 = nt * 64;
  int og = threadIdx.x & 15;
  int ng = threadIdx.x >> 4;
  float acc[4][4] = {};
  for (int ct = 0; ct < 8; ++ct) {
    __syncthreads();
    {
      int e = threadIdx.x;
#pragma unroll
      for (int it = 0; it < 2; ++it, e += 256) {
        int row = e >> 3, c4 = e & 7;
        float4 v = *(const float4*)&h1[((size_t)(b * NPTS + n0 + row)) * 256 + ct * 32 + c4 * 4];
        *(float4*)&As[row][c4 * 4] = v;
      }
    }
    {
      int e = threadIdx.x;
#pragma unroll
      for (int it = 0; it < 2; ++it, e += 256) {
        int row = e >> 4, c16 = e & 15;
        float4 v = *(const float4*)&Wf[((size_t)(ct * 32 + row)) * 512 + o0 + c16 * 4];
        *(float4*)&Bs[row][c16 * 4] = v;
      }
    }
    __syncthreads();
#pragma unroll
    for (int c4 = 0; c4 < 8; ++c4) {
      float4 av[4], bv[4];
#pragma unroll
      for (int u = 0; u < 4; ++u) av[u] = *(const float4*)&As[ng * 4 + u][c4 * 4];
#pragma unroll
      for (int u = 0; u < 4; ++u) bv[u] = *(const float4*)&Bs[c4 * 4 + u][og * 4];
#pragma unroll
      for (int nn = 0; nn < 4; ++nn) {
        float a0 = av[nn].x, a1 = av[nn].y, a2 = av[nn].z, a3 = av[nn].w;
        acc[nn][0] += a0 * bv[0].x + a1 * bv[1].x + a2 * bv[2].x + a3 * bv[3].x;
        acc[nn][1] += a0 * bv[0].y + a1 * bv[1].y + a2 * bv[2].y + a3 * bv[3].y;
        acc[nn][2] += a0 * bv[0].z + a1 * bv[1].z + a2 * bv[2].z + a3 * bv[3].z;
        acc[nn][3] += a0 * bv[0].w + a1 * bv[1].w + a2 * bv[2].w + a3 * bv[3].w;
      }
    }
  }
  float po[4] = {0.f, 0.f, 0.f, 0.f};
#pragma unroll
  for (int nn = 0; nn < 4; ++nn) {
    float al = alpha[(size_t)b * NPTS + n0 + ng * 4 + nn];
#pragma unroll
    for (int oo = 0; oo < 4; ++oo) {
      float f = acc[nn][oo] + bf[o0 + og * 4 + oo];
      f = fmaxf(f, 0.f);
      po[oo] += al * f;
    }
  }
  __syncthreads();
  *(float4*)&Rs[ng][og * 4] = make_float4(po[0], po[1], po[2], po[3]);
  __syncthreads();
  if (threadIdx.x < 64) {
    float s2 = 0.f;
#pragma unroll
    for (int gg = 0; gg < 16; ++gg) s2 += Rs[gg][threadIdx.x];
    atomicAdd(&pooled[(size_t)b * DF + o0 + threadIdx.x], s2);
  }
}

// ---------------- out = pooled @ Wl + bl ----------------
__global__ __launch_bounds__(256) void final_kernel(
    const float* __restrict__ pooled, const float* __restrict__ Wl,
    const float* __restrict__ bl, float* __restrict__ out) {
  __shared__ float ps[DF];
  int b = blockIdx.x, j = threadIdx.x;
  for (int e = threadIdx.x; e < DF; e += 256) ps[e] = pooled[(size_t)b * DF + e];
  __syncthreads();
  float a0 = 0.f, a1 = 0.f, a2 = 0.f, a3 = 0.f;
  for (int o = 0; o < DF; o += 4) {
    a0 += ps[o + 0] * Wl[(size_t)(o + 0) * DOUT + j];
    a1 += ps[o + 1] * Wl[(size_t)(o + 1) * DOUT + j];
    a2 += ps[o + 2] * Wl[(size_t)(o + 2) * DOUT + j];
    a3 += ps[o + 3] * Wl[(size_t)(o + 3) * DOUT + j];
  }
  out[(size_t)b * DOUT + j] = (a0 + a1) + (a2 + a3) + bl[j];
}

// ---------------- launch ----------------
extern "C" void kernel_launch(void* const* d_in, const int* in_sizes, int n_in,
                              void* d_out, int out_size, void* d_ws, size_t ws_size,
                              hipStream_t stream) {
  (void)in_sizes; (void)n_in; (void)out_size; (void)ws_size;
  const float* x   = (const float*)d_in[0];
  const float* Wt0 = (const float*)d_in[1];
  const float* bt0 = (const float*)d_in[2];
  const float* Wp0 = (const float*)d_in[3];
  const float* bp0 = (const float*)d_in[4];
  const float* g0  = (const float*)d_in[5];
  const float* be0 = (const float*)d_in[6];
  const float* Wt1 = (const float*)d_in[7];
  const float* bt1 = (const float*)d_in[8];
  const float* Wp1 = (const float*)d_in[9];
  const float* bp1 = (const float*)d_in[10];
  const float* g1  = (const float*)d_in[11];
  const float* be1 = (const float*)d_in[12];
  const float* Wg  = (const float*)d_in[13];
  const float* bg  = (const float*)d_in[14];
  const float* Wf  = (const float*)d_in[15];
  const float* bf  = (const float*)d_in[16];
  const float* Wl  = (const float*)d_in[17];
  const float* bl  = (const float*)d_in[18];
  float* out = (float*)d_out;
  char* ws = (char*)d_ws;

  float* H0     = (float*)(ws + OFF_H0);
  unsigned* VMM0 = (unsigned*)(ws + OFF_H0);    // in-place with H0
  int*   IDX0   = (int*)  (ws + OFF_IDX0);
  int*   IDX1   = (int*)  (ws + OFF_IDX1);
  float* D2     = (float*)(ws + OFF_D2);
  float* GATE   = (float*)(ws + OFF_GATE);
  float* ALPHA  = (float*)(ws + OFF_ALPHA);
  float* SS0    = (float*)(ws + OFF_SS0);
  float* SS1    = (float*)(ws + OFF_SS1);
  float* STATS0 = (float*)(ws + OFF_STATS0);
  float* STATS1 = (float*)(ws + OFF_STATS1);
  float* POOLED = (float*)(ws + OFF_POOLED);
  float* P1     = (float*)(ws + OFF_P1);
  float* Q1     = (float*)(ws + OFF_Q1);
  float* H1     = (float*)(ws + OFF_H1);
  unsigned* VMM1 = (unsigned*)(ws + OFF_H1);    // in-place with H1
  float* P0     = (float*)(ws + OFF_P0);
  float* Q0     = (float*)(ws + OFF_Q0);
  unsigned short* AB = (unsigned short*)(ws + OFF_AB);
  unsigned* PDU = (unsigned*)(ws + OFF_PDU);
  unsigned short* U0 = (unsigned short*)(ws + OFF_U0);
  unsigned short* V0 = (unsigned short*)(ws + OFF_V0);

  hipMemsetAsync(ws + ZERO_OFF, 0, ZERO_BYTES, stream);

  // ----- layer 0: knn on xyz (MFMA packed split), EdgeConv 3->64 -----
  d2x_kernel<<<BN / 256, 256, 0, stream>>>(x, D2);
  usplit0_kernel<<<BN / 256, 256, 0, stream>>>(x, U0, V0);
  knn_mfsel_kernel<32, 40, 4><<<(BN / 64) * 4, 256, 0, stream>>>(V0, U0, D2, PDU);
  knn_mergek_kernel<4><<<BN / 256, 256, 0, stream>>>(PDU, IDX0);
  pq0_kernel<<<BN * 64 / 256, 256, 0, stream>>>(x, Wt0, bt0, Wp0, bp0, P0, Q0);
  bn_gather_kernel<64, 32><<<BN / 32, 256, 0, stream>>>(P0, Q0, IDX0, STATS0, VMM0);
  bn_final_kernel<64><<<1, 64, 0, stream>>>(STATS0, g0, be0, SS0);
  apply0_kernel<<<BN / 4, 256, 0, stream>>>(VMM0, SS0, H0, AB, D2);

  // ----- layer 1: knn on 64-d features (MFMA bf16-split), EdgeConv 64->256 -----
  knn_mfsel_kernel<128, 136, 4><<<(BN / 64) * 4, 256, 0, stream>>>(AB, AB, D2, PDU);
  knn_mergek_kernel<4><<<BN / 256, 256, 0, stream>>>(PDU, IDX1);
  pq1_kernel<<<BN / 32, 256, 0, stream>>>(H0, Wt1, bt1, Wp1, bp1, P1, Q1);
  bn_gather_kernel<256, 16><<<BN / 16, 256, 0, stream>>>(P1, Q1, IDX1, STATS1, VMM1);
  bn_final_kernel<256><<<1, 256, 0, stream>>>(STATS1, g1, be1, SS1);
  apply1_kernel<<<BN / 4, 256, 0, stream>>>(VMM1, SS1, Wg, bg, H1, GATE);

  // ----- attention pooling + final linear -----
  softmax_kernel<<<NBATCH, 256, 0, stream>>>(GATE, ALPHA);
  featpool_kernel<<<NBATCH * 64 * 8, 256, 0, stream>>>(H1, Wf, bf, ALPHA, POOLED);
  final_kernel<<<NBATCH, 256, 0, stream>>>(POOLED, Wl, bl, out);
}